// Round 12
// baseline (190.498 us; speedup 1.0000x reference)
//
#include <hip/hip_runtime.h>

// ---------------- constants ----------------
// B=16, CIN=256, COUT=256, H=W=64, K=3, SDIM=128
// Separable reformulation:
//   out[b,co,p] = demod[b,co] * sum_{t,ci} wsh[t,co,ci] * y[b,ci,p+shift(t)]
//   wsh = conv_scale * w  (batch-independent!),  y = s[b,ci] * x[b,ci,p]
//   demod[b,co] = rsqrt( sum_ci G[co,ci] * s[b,ci]^2 + 1e-8 ),  G = sum_t wsh^2
// ws layout (bytes):
//   xpad  bf16 [16][66][66][256] : 0          .. 35,684,352   (holds y, padded NHWC)
//   wsh   bf16 [9][256][256]     : 35,684,352 .. 36,864,000
//   s     f32  [16][256]         : 36,864,000 .. 36,880,384
//   G     f32  [256][256]        : 36,880,384 .. 37,142,528
//   demod f32  [16][256]         : 37,142,528 .. 37,158,912

#define WSH_OFF    35684352
#define S_OFF      36864000
#define G_OFF      36880384
#define DEMOD_OFF  37142528

typedef __attribute__((ext_vector_type(8))) short bf16x8;
typedef __attribute__((ext_vector_type(4))) float f32x4;
typedef __attribute__((ext_vector_type(4))) int i32x4;

#define GLOAD_LDS16(g, l)                                                        \
  __builtin_amdgcn_global_load_lds(                                              \
      (const __attribute__((address_space(1))) void*)(g),                        \
      (__attribute__((address_space(3))) void*)(l), 16, 0, 0)

__device__ __forceinline__ unsigned short f2bf(float f) {
  unsigned int u = __builtin_bit_cast(unsigned int, f);
  u += 0x7FFFu + ((u >> 16) & 1u);  // round-to-nearest-even
  return (unsigned short)(u >> 16);
}

// ---------------- kernel 1: style s[b][i]  +  shared weights & G ----------------
__global__ void prep1_k(const float* __restrict__ c_trg,
                        const float* __restrict__ style_w,
                        const float* __restrict__ style_b,
                        const float* __restrict__ weight,
                        float* __restrict__ s,
                        short* __restrict__ wsh,
                        float* __restrict__ G) {
  const int blk = blockIdx.x;
  const int tid = threadIdx.x;
  if (blk < 16) {
    const int b = blk;
    const float* ct = c_trg + b * 128;
    const float* sw = style_w + tid * 128;
    float acc = 0.f;
#pragma unroll 4
    for (int d = 0; d < 128; ++d) acc += ct[d] * sw[d];
    s[b * 256 + tid] = acc * 0.08838834764831845f + style_b[tid];  // 1/sqrt(128)
  } else {
    const int idx = (blk - 16) * 256 + tid;  // co*256+ci
    const float* wsrc = weight + idx * 9;    // 9 contiguous taps
    float g = 0.f;
#pragma unroll
    for (int t = 0; t < 9; ++t) {
      float v = wsrc[t] * 0.020833333333333332f;  // 1/sqrt(2304)
      g += v * v;
      wsh[t * 65536 + idx] = (short)f2bf(v);
    }
    G[idx] = g;
  }
}

// ---------------- kernel 2: y = s*x transpose + border zero + demod (fused grid) ----
__global__ void xpose_k(const float* __restrict__ x,
                        const float* __restrict__ s,
                        const float* __restrict__ G,
                        short* __restrict__ xpad,
                        float* __restrict__ demod) {
  __shared__ float tile[64][65];
  const int bid = blockIdx.x;
  const int tid = threadIdx.x;
  if (bid >= 4112) {
    // demod: block = b*256+co
    const int id = bid - 4112;
    const int b = id >> 8, co = id & 255;
    const float sv = s[b * 256 + tid];
    float ss = G[co * 256 + tid] * sv * sv;
#pragma unroll
    for (int o = 32; o; o >>= 1) ss += __shfl_down(ss, o);
    __shared__ float red[4];
    if ((tid & 63) == 0) red[tid >> 6] = ss;
    __syncthreads();
    if (tid == 0) demod[id] = rsqrtf(red[0] + red[1] + red[2] + red[3] + 1e-8f);
    return;
  }
  if (bid >= 4096) {
    const int b = bid - 4096;
    char* base = (char*)xpad + b * 66 * 66 * 512;
    const i32x4 z = {0, 0, 0, 0};
    for (int i = tid; i < 4224; i += 256) {
      const int r = i >= 2112;
      const int off = r * (65 * 66 * 512) + (i - r * 2112) * 16;
      *(i32x4*)(base + off) = z;
    }
    for (int i = tid; i < 4096; i += 256) {
      const int h = 1 + (i >> 6);
      const int side = (i >> 5) & 1;
      const int j = i & 31;
      *(i32x4*)(base + (h * 66 + side * 65) * 512 + j * 16) = z;
    }
    return;
  }
  const int ct = bid & 3;
  const int h = (bid >> 2) & 63;
  const int b = bid >> 8;
  const int w = tid & 63, cl = tid >> 6;
  const float* src = x + ((b * 256 + ct * 64) * 64 + h) * 64;
#pragma unroll
  for (int i = 0; i < 16; ++i) {
    int c = i * 4 + cl;
    tile[c][w] = src[c * 4096 + w];
  }
  const int cp = tid & 31;
  const float s0 = s[b * 256 + ct * 64 + cp * 2];
  const float s1 = s[b * 256 + ct * 64 + cp * 2 + 1];
  __syncthreads();
  short* dst = xpad + ((b * 66 + h + 1) * 66 + 1) * 256 + ct * 64;
#pragma unroll
  for (int i = 0; i < 8; ++i) {
    int idx = i * 256 + tid;
    int w2 = idx >> 5;  // 0..63
    unsigned int u = (unsigned int)f2bf(tile[cp * 2][w2] * s0) |
                     ((unsigned int)f2bf(tile[cp * 2 + 1][w2] * s1) << 16);
    *(unsigned int*)(dst + w2 * 256 + cp * 2) = u;
  }
}

// ---------------- kernel 3: implicit-GEMM conv, 256x256, BK=64, A-from-L2 ----------
// 512 thr = 8 waves (2M x 4N), wave tile 128x64.
// r12 change: A (wsh) is 1.15 MB shared by ALL blocks -> pinned in every XCD L2
// by the XCD swizzle. Staging it through LDS was pure overhead (catalog common-
// mistake #7): it was 16 of 24 ds_reads/wave/tile + half the staging writes.
// Now A fragments load DIRECTLY global->VGPR (plain C++ loads; compiler emits
// counted vmcnt). Lane mapping: frag(m,kc): row = wm*128+m*16+(lane&15),
// byte col = cc*128 + kc*64 + (lane>>4)*16; lanes {l,l+16,l+32,l+48} share one
// 64B segment -> 16 cache lines per load, L2-hit (~200cy, hidden by B reads).
// LDS now carries ONLY B: 2 dbuf x 32 KB = 64 KB. Per-tile CU budget: MFMA 2484
// cyc + LDS (512 rd + 256 wr) vs old 2048 -> serial-sum bound drops ~27%.
// Drift schedule, ONE sync/tile (vmcnt(0)+barrier): stageB(t+1) targets buf
// (t+1)&1 = tile t-1's buffer (reads data-dep retired before each wave reached
// this tile's barrier). No setprio/pins (r10/r11: null).
// T1: XCD swizzle (grid 256) -> 2 samples per XCD L2.
// T2: XOR swizzle byte ^= ((row&7)<<4) on B: linear LDS dest, inverse-swizzled
//     global source, swizzled ds_read; 16x16 frag rows span lane&15 -> 2-way
//     bank aliasing max = free (measured 0 conflicts).
__global__ __launch_bounds__(512, 2) void conv_k(const short* __restrict__ xpad,
                                                 const short* __restrict__ wsh,
                                                 const float* __restrict__ demod,
                                                 float* __restrict__ out) {
  extern __shared__ __align__(16) char lds[];  // 65536 B (B double-buffer only)

  const int tid = threadIdx.x;
  const int lane = tid & 63;
  const int wid = tid >> 6;
  const int wm = wid >> 2;   // 0..1 : cout half
  const int wn = wid & 3;    // 0..3 : pixel quarter (output row r0+wn)

  const int orig = blockIdx.x;
  const int bid = (orig & 7) * 32 + (orig >> 3);  // T1
  const int b = bid >> 4;
  const int r0 = (bid & 15) * 4;  // 4 output rows per block

  // B staging: per K-tile 4 x 16B loads/thread. Load j covers LDS rows j*64+t3,
  // byte col (tid&7)*16 (linear dest); source col pre-swizzled (row&7 == t3&7).
  const int t3 = tid >> 3;
  const int c16 = (tid & 7) * 16;
  const int swzc = c16 ^ ((t3 & 7) << 4);
  int bO[4];
#pragma unroll
  for (int j = 0; j < 4; ++j)
    bO[j] = ((b * 66 + r0 + j) * 66 + t3) * 512 + swzc;   // + (dh*66+dw)*512 + cc*128
  const char* wB = (const char*)wsh;
  const char* xB = (const char*)xpad;

  auto stageB = [&](int ts) {
    const int tap = ts >> 2, cc = ts & 3;
    const int dh = (tap * 11) >> 5;  // tap/3
    const int bAdd = (dh * 66 + (tap - dh * 3)) * 512 + cc * 128;
    char* d = lds + (ts & 1) * 32768;
#pragma unroll
    for (int j = 0; j < 4; ++j)
      GLOAD_LDS16(xB + bAdd + bO[j], d + j * 8192 + tid * 16);
  };

  // B read side (T2): col_read = col ^ ((row&7)<<4); row&7 == lane&7.
  const int xall = (lane & 7) << 4;
  const int xl = xall & 0x30;
  const int xh = xall & 0x40;
  const int colR = (((lane >> 4) << 4) ^ xl);
  const int ko0 = xh;
  const int ko1 = 64 ^ xh;
  const int bRdBase = (wn * 64 + (lane & 15)) * 128 + colR;

  // A direct-load base: frag(m,kc) at wB + tap*131072 + cc*128 + aBase + m*8192 + kc*64
  const int aBase = (wm * 128 + (lane & 15)) * 512 + (lane >> 4) * 16;

  f32x4 acc[8][4] = {};

  stageB(0);

  for (int t = 0; t < 36; ++t) {
    // single sync point per K-tile (drains stageB(t), issued during tile t-1)
    asm volatile("s_waitcnt vmcnt(0)" ::: "memory");
    __builtin_amdgcn_s_barrier();
    __builtin_amdgcn_sched_barrier(0);

    const int tap = t >> 2, cc = t & 3;
    const char* aT = wB + tap * 131072 + cc * 128 + aBase;
    const char* Bb = lds + (t & 1) * 32768 + bRdBase;
    bf16x8 a03[4][2], a47[4][2], bq[4][2];

    // A group 0/1 (global->reg, L2-hot; compiler-counted vmcnt)
#pragma unroll
    for (int m = 0; m < 4; ++m) {
      a03[m][0] = *(const bf16x8*)(aT + m * 8192);
      a03[m][1] = *(const bf16x8*)(aT + m * 8192 + 64);
    }
    // B reads (LDS)
#pragma unroll
    for (int n = 0; n < 4; ++n) {
      bq[n][0] = *(const bf16x8*)(Bb + n * 2048 + ko0);
      bq[n][1] = *(const bf16x8*)(Bb + n * 2048 + ko1);
    }
    if (t + 1 < 36) stageB(t + 1);

    // M1: m0-3, kc0
#pragma unroll
    for (int m = 0; m < 4; ++m)
#pragma unroll
      for (int n = 0; n < 4; ++n)
        acc[m][n] = __builtin_amdgcn_mfma_f32_16x16x32_bf16(a03[m][0], bq[n][0], acc[m][n], 0, 0, 0);

    // A group 2/3 (in flight during M2)
#pragma unroll
    for (int m = 0; m < 4; ++m) {
      a47[m][0] = *(const bf16x8*)(aT + (m + 4) * 8192);
      a47[m][1] = *(const bf16x8*)(aT + (m + 4) * 8192 + 64);
    }

    // M2: m0-3, kc1
#pragma unroll
    for (int m = 0; m < 4; ++m)
#pragma unroll
      for (int n = 0; n < 4; ++n)
        acc[m][n] = __builtin_amdgcn_mfma_f32_16x16x32_bf16(a03[m][1], bq[n][1], acc[m][n], 0, 0, 0);

    // M3: m4-7, kc0
#pragma unroll
    for (int m = 0; m < 4; ++m)
#pragma unroll
      for (int n = 0; n < 4; ++n)
        acc[m + 4][n] = __builtin_amdgcn_mfma_f32_16x16x32_bf16(a47[m][0], bq[n][0], acc[m + 4][n], 0, 0, 0);

    // M4: m4-7, kc1
#pragma unroll
    for (int m = 0; m < 4; ++m)
#pragma unroll
      for (int n = 0; n < 4; ++n)
        acc[m + 4][n] = __builtin_amdgcn_mfma_f32_16x16x32_bf16(a47[m][1], bq[n][1], acc[m + 4][n], 0, 0, 0);

    asm volatile("" ::: "memory");
  }

  // epilogue: scale by demod[b][cout], store fp32 NCHW.
  const int pc = lane & 15;
  const int rOff = (lane >> 4) * 4;
  const int h = r0 + wn;
#pragma unroll
  for (int m = 0; m < 8; ++m) {
#pragma unroll
    for (int r = 0; r < 4; ++r) {
      const int co = wm * 128 + m * 16 + rOff + r;
      const float dm = demod[(b << 8) + co];
      float* orow = out + (((b << 8) + co) << 12) + (h << 6);
#pragma unroll
      for (int n = 0; n < 4; ++n) {
        orow[n * 16 + pc] = acc[m][n][r] * dm;
      }
    }
  }
}

// ---------------- launcher ----------------
extern "C" void kernel_launch(void* const* d_in, const int* in_sizes, int n_in,
                              void* d_out, int out_size, void* d_ws, size_t ws_size,
                              hipStream_t stream) {
  const float* x       = (const float*)d_in[0];
  // d_in[1] = c_src (unused by reference)
  const float* c_trg   = (const float*)d_in[2];
  const float* style_w = (const float*)d_in[3];
  const float* style_b = (const float*)d_in[4];
  const float* weight  = (const float*)d_in[5];
  float* out = (float*)d_out;

  char* ws = (char*)d_ws;
  short* xpad  = (short*)(ws);
  short* wsh   = (short*)(ws + WSH_OFF);
  float* s     = (float*)(ws + S_OFF);
  float* G     = (float*)(ws + G_OFF);
  float* demod = (float*)(ws + DEMOD_OFF);

  hipFuncSetAttribute((const void*)conv_k,
                      hipFuncAttributeMaxDynamicSharedMemorySize, 65536);

  prep1_k<<<272, 256, 0, stream>>>(c_trg, style_w, style_b, weight, s, wsh, G);
  xpose_k<<<8208, 256, 0, stream>>>(x, s, G, xpad, demod);
  conv_k<<<256, 512, 65536, stream>>>(xpad, wsh, demod, out);
}

// Round 13
// 177.143 us; speedup vs baseline: 1.0754x; 1.0754x over previous
//
#include <hip/hip_runtime.h>

// ---------------- constants ----------------
// B=16, CIN=256, COUT=256, H=W=64, K=3, SDIM=128
// Separable reformulation:
//   out[b,co,p] = demod[b,co] * sum_{t,ci} wsh[t,co,ci] * y[b,ci,p+shift(t)]
//   wsh = conv_scale * w  (batch-independent!),  y = s[b,ci] * x[b,ci,p]
//   demod[b,co] = rsqrt( sum_ci G[co,ci] * s[b,ci]^2 + 1e-8 ),  G = sum_t wsh^2
// ws layout (bytes):
//   xpad  bf16 [16][66][66][256] : 0          .. 35,684,352   (holds y, padded NHWC)
//   wsh   bf16 [9][256][256]     : 35,684,352 .. 36,864,000
//   s     f32  [16][256]         : 36,864,000 .. 36,880,384
//   G     f32  [256][256]        : 36,880,384 .. 37,142,528
//   demod f32  [16][256]         : 37,142,528 .. 37,158,912

#define WSH_OFF    35684352
#define S_OFF      36864000
#define G_OFF      36880384
#define DEMOD_OFF  37142528

typedef __attribute__((ext_vector_type(8))) short bf16x8;
typedef __attribute__((ext_vector_type(4))) float f32x4;
typedef __attribute__((ext_vector_type(4))) int i32x4;

#define GLOAD_LDS16(g, l)                                                        \
  __builtin_amdgcn_global_load_lds(                                              \
      (const __attribute__((address_space(1))) void*)(g),                        \
      (__attribute__((address_space(3))) void*)(l), 16, 0, 0)

__device__ __forceinline__ unsigned short f2bf(float f) {
  unsigned int u = __builtin_bit_cast(unsigned int, f);
  u += 0x7FFFu + ((u >> 16) & 1u);  // round-to-nearest-even
  return (unsigned short)(u >> 16);
}

// ---------------- kernel 1: style s[b][i]  +  shared weights & G ----------------
__global__ void prep1_k(const float* __restrict__ c_trg,
                        const float* __restrict__ style_w,
                        const float* __restrict__ style_b,
                        const float* __restrict__ weight,
                        float* __restrict__ s,
                        short* __restrict__ wsh,
                        float* __restrict__ G) {
  const int blk = blockIdx.x;
  const int tid = threadIdx.x;
  if (blk < 16) {
    const int b = blk;
    const float* ct = c_trg + b * 128;
    const float* sw = style_w + tid * 128;
    float acc = 0.f;
#pragma unroll 4
    for (int d = 0; d < 128; ++d) acc += ct[d] * sw[d];
    s[b * 256 + tid] = acc * 0.08838834764831845f + style_b[tid];  // 1/sqrt(128)
  } else {
    const int idx = (blk - 16) * 256 + tid;  // co*256+ci
    const float* wsrc = weight + idx * 9;    // 9 contiguous taps
    float g = 0.f;
#pragma unroll
    for (int t = 0; t < 9; ++t) {
      float v = wsrc[t] * 0.020833333333333332f;  // 1/sqrt(2304)
      g += v * v;
      wsh[t * 65536 + idx] = (short)f2bf(v);
    }
    G[idx] = g;
  }
}

// ---------------- kernel 2: y = s*x transpose + border zero + demod (fused grid) ----
__global__ void xpose_k(const float* __restrict__ x,
                        const float* __restrict__ s,
                        const float* __restrict__ G,
                        short* __restrict__ xpad,
                        float* __restrict__ demod) {
  __shared__ float tile[64][65];
  const int bid = blockIdx.x;
  const int tid = threadIdx.x;
  if (bid >= 4112) {
    // demod: block = b*256+co
    const int id = bid - 4112;
    const int b = id >> 8, co = id & 255;
    const float sv = s[b * 256 + tid];
    float ss = G[co * 256 + tid] * sv * sv;
#pragma unroll
    for (int o = 32; o; o >>= 1) ss += __shfl_down(ss, o);
    __shared__ float red[4];
    if ((tid & 63) == 0) red[tid >> 6] = ss;
    __syncthreads();
    if (tid == 0) demod[id] = rsqrtf(red[0] + red[1] + red[2] + red[3] + 1e-8f);
    return;
  }
  if (bid >= 4096) {
    const int b = bid - 4096;
    char* base = (char*)xpad + b * 66 * 66 * 512;
    const i32x4 z = {0, 0, 0, 0};
    for (int i = tid; i < 4224; i += 256) {
      const int r = i >= 2112;
      const int off = r * (65 * 66 * 512) + (i - r * 2112) * 16;
      *(i32x4*)(base + off) = z;
    }
    for (int i = tid; i < 4096; i += 256) {
      const int h = 1 + (i >> 6);
      const int side = (i >> 5) & 1;
      const int j = i & 31;
      *(i32x4*)(base + (h * 66 + side * 65) * 512 + j * 16) = z;
    }
    return;
  }
  const int ct = bid & 3;
  const int h = (bid >> 2) & 63;
  const int b = bid >> 8;
  const int w = tid & 63, cl = tid >> 6;
  const float* src = x + ((b * 256 + ct * 64) * 64 + h) * 64;
#pragma unroll
  for (int i = 0; i < 16; ++i) {
    int c = i * 4 + cl;
    tile[c][w] = src[c * 4096 + w];
  }
  const int cp = tid & 31;
  const float s0 = s[b * 256 + ct * 64 + cp * 2];
  const float s1 = s[b * 256 + ct * 64 + cp * 2 + 1];
  __syncthreads();
  short* dst = xpad + ((b * 66 + h + 1) * 66 + 1) * 256 + ct * 64;
#pragma unroll
  for (int i = 0; i < 8; ++i) {
    int idx = i * 256 + tid;
    int w2 = idx >> 5;  // 0..63
    unsigned int u = (unsigned int)f2bf(tile[cp * 2][w2] * s0) |
                     ((unsigned int)f2bf(tile[cp * 2 + 1][w2] * s1) << 16);
    *(unsigned int*)(dst + w2 * 256 + cp * 2) = u;
  }
}

// ---------------- kernel 3: implicit-GEMM conv, 256x256, BK=64, FAT wave tile -------
// r13 change: 4 waves (1/SIMD), wave tile 128x128 (2Mx2N). LDS-read bytes/FLOP
// halve per CU: 4 waves x 32 reads = 128 KB/tile/CU (was 8 x 24 = 192 KB).
// Serial-sum bound drops 4560 -> ~3570 cyc/tile. MFMA/read per wave: 128/32
// (was 64/24). acc = 8x8 f32x4 = 256 regs; legal at 1 wave/SIMD (512 budget),
// __launch_bounds__(256,1). A and B BOTH via LDS (r12 lesson: per-lane-K
// operand layouts need LDS; L2-direct gathers 16 lines/load = slower).
// Schedule: r7/r10 drift structure, ONE sync point per tile (vmcnt(0)+barrier),
// unpinned interior (compiler emits counted lgkmcnt), no setprio (m190 null).
// Staging: 256 thr x 16 loads/tile (A 8 + B 8, 16B each), targets buf (t+1)&1
// = tile t-1's buffer (reads data-dep retired before this tile's top barrier).
// T1: XCD swizzle (grid 256) -> 2 samples per XCD L2.
// T2: XOR swizzle byte ^= ((row&7)<<4): linear LDS dest, inverse-swizzled
//     global source, swizzled ds_read; frag rows span lane&15 -> 2-way max =
//     free (measured 0 conflicts in this exact layout, r7/r10).
__global__ __launch_bounds__(256, 1) void conv_k(const short* __restrict__ xpad,
                                                 const short* __restrict__ wsh,
                                                 const float* __restrict__ demod,
                                                 float* __restrict__ out) {
  extern __shared__ __align__(16) char lds[];  // 131072 B: 2 bufs x (A 32K | B 32K)

  const int tid = threadIdx.x;
  const int lane = tid & 63;
  const int wid = tid >> 6;
  const int wm = wid >> 1;   // 0..1 : cout half (128)
  const int wn = wid & 1;    // 0..1 : pixel half (128)

  const int orig = blockIdx.x;
  const int bid = (orig & 7) * 32 + (orig >> 3);  // T1, grid=256
  const int b = bid >> 4;
  const int r0 = (bid & 15) * 4;  // 4 output rows per block

  // staging: per K-tile 8 A-loads + 8 B-loads per thread (16 B each).
  // chunk j covers LDS rows j*32 + t3 (t3 = tid>>3, 0..31), byte col (tid&7)*16
  // (linear dest); source col pre-swizzled: c16 ^ ((row&7)<<4), row&7 == t3&7.
  const int t3 = tid >> 3;
  const int c16 = (tid & 7) * 16;
  const int swzc = c16 ^ ((t3 & 7) << 4);
  int aO[8], bO[8];
#pragma unroll
  for (int j = 0; j < 8; ++j) {
    const int p = j * 32 + t3;  // row 0..255
    aO[j] = p * 512 + swzc;                                   // + tap*131072 + cc*128
    bO[j] = ((b * 66 + r0 + (p >> 6)) * 66 + (p & 63)) * 512 + swzc;
  }
  const char* wB = (const char*)wsh;
  const char* xB = (const char*)xpad;

  auto stageA = [&](int ts) {
    const int tap = ts >> 2, cc = ts & 3;
    const int aAdd = tap * 131072 + cc * 128;
    char* d = lds + (ts & 1) * 65536;
#pragma unroll
    for (int j = 0; j < 8; ++j)
      GLOAD_LDS16(wB + aAdd + aO[j], d + j * 4096 + tid * 16);
  };
  auto stageB = [&](int ts) {
    const int tap = ts >> 2, cc = ts & 3;
    const int dh = (tap * 11) >> 5;  // tap/3
    const int bAdd = (dh * 66 + (tap - dh * 3)) * 512 + cc * 128;
    char* d = lds + (ts & 1) * 65536 + 32768;
#pragma unroll
    for (int j = 0; j < 8; ++j)
      GLOAD_LDS16(xB + bAdd + bO[j], d + j * 4096 + tid * 16);
  };

  // T2 read side: col_read = col ^ ((row&7)<<4); row&7 == lane&7 everywhere.
  const int xall = (lane & 7) << 4;
  const int xl = xall & 0x30;
  const int xh = xall & 0x40;
  const int colR = (((lane >> 4) << 4) ^ xl);
  const int ko0 = xh;
  const int ko1 = 64 ^ xh;
  const int aRdBase = (wm * 128 + (lane & 15)) * 128 + colR;
  const int bRdBase = 32768 + (wn * 128 + (lane & 15)) * 128 + colR;

  f32x4 acc[8][8] = {};

  stageA(0);
  stageB(0);

  for (int t = 0; t < 36; ++t) {
    // single sync point per K-tile (publishes stage(t), issued during tile t-1)
    asm volatile("s_waitcnt vmcnt(0)" ::: "memory");
    __builtin_amdgcn_s_barrier();
    __builtin_amdgcn_sched_barrier(0);

    const char* Ab = lds + (t & 1) * 65536 + aRdBase;
    const char* Bb = lds + (t & 1) * 65536 + bRdBase;
    bf16x8 af[8], bq[8];

    // ---- kc0: 16 ds_read ; stage A(t+1) ; 64 MFMA ----
#pragma unroll
    for (int m = 0; m < 8; ++m) af[m] = *(const bf16x8*)(Ab + m * 2048 + ko0);
#pragma unroll
    for (int n = 0; n < 8; ++n) bq[n] = *(const bf16x8*)(Bb + n * 2048 + ko0);
    if (t + 1 < 36) stageA(t + 1);
#pragma unroll
    for (int m = 0; m < 8; ++m)
#pragma unroll
      for (int n = 0; n < 8; ++n)
        acc[m][n] = __builtin_amdgcn_mfma_f32_16x16x32_bf16(af[m], bq[n], acc[m][n], 0, 0, 0);

    // ---- kc1: 16 ds_read ; stage B(t+1) ; 64 MFMA ----
#pragma unroll
    for (int m = 0; m < 8; ++m) af[m] = *(const bf16x8*)(Ab + m * 2048 + ko1);
#pragma unroll
    for (int n = 0; n < 8; ++n) bq[n] = *(const bf16x8*)(Bb + n * 2048 + ko1);
    if (t + 1 < 36) stageB(t + 1);
#pragma unroll
    for (int m = 0; m < 8; ++m)
#pragma unroll
      for (int n = 0; n < 8; ++n)
        acc[m][n] = __builtin_amdgcn_mfma_f32_16x16x32_bf16(af[m], bq[n], acc[m][n], 0, 0, 0);

    asm volatile("" ::: "memory");
  }

  // epilogue: scale by demod[b][cout], store fp32 NCHW.
  const int pc = lane & 15;
  const int rOff = (lane >> 4) * 4;
#pragma unroll
  for (int m = 0; m < 8; ++m) {
#pragma unroll
    for (int r = 0; r < 4; ++r) {
      const int co = wm * 128 + m * 16 + rOff + r;
      const float dm = demod[(b << 8) + co];
      float* obase = out + (((b << 8) + co) << 12);
#pragma unroll
      for (int n = 0; n < 8; ++n) {
        const int pix = wn * 128 + n * 16 + pc;
        const int h = r0 + (pix >> 6), w = pix & 63;
        obase[(h << 6) + w] = acc[m][n][r] * dm;
      }
    }
  }
}

// ---------------- launcher ----------------
extern "C" void kernel_launch(void* const* d_in, const int* in_sizes, int n_in,
                              void* d_out, int out_size, void* d_ws, size_t ws_size,
                              hipStream_t stream) {
  const float* x       = (const float*)d_in[0];
  // d_in[1] = c_src (unused by reference)
  const float* c_trg   = (const float*)d_in[2];
  const float* style_w = (const float*)d_in[3];
  const float* style_b = (const float*)d_in[4];
  const float* weight  = (const float*)d_in[5];
  float* out = (float*)d_out;

  char* ws = (char*)d_ws;
  short* xpad  = (short*)(ws);
  short* wsh   = (short*)(ws + WSH_OFF);
  float* s     = (float*)(ws + S_OFF);
  float* G     = (float*)(ws + G_OFF);
  float* demod = (float*)(ws + DEMOD_OFF);

  hipFuncSetAttribute((const void*)conv_k,
                      hipFuncAttributeMaxDynamicSharedMemorySize, 131072);

  prep1_k<<<272, 256, 0, stream>>>(c_trg, style_w, style_b, weight, s, wsh, G);
  xpose_k<<<8208, 256, 0, stream>>>(x, s, G, xpad, demod);
  conv_k<<<256, 256, 131072, stream>>>(xpad, wsh, demod, out);
}

// Round 14
// 102.712 us; speedup vs baseline: 1.8547x; 1.7247x over previous
//
#include <hip/hip_runtime.h>

// ---------------- constants ----------------
// B=16, CIN=256, COUT=256, H=W=64, K=3, SDIM=128
// Separable reformulation:
//   out[b,co,p] = demod[b,co] * sum_{t,ci} wsh[t,co,ci] * y[b,ci,p+shift(t)]
//   wsh = conv_scale * w  (batch-independent!),  y = s[b,ci] * x[b,ci,p]
//   demod[b,co] = rsqrt( sum_ci G[co,ci] * s[b,ci]^2 + 1e-8 ),  G = sum_t wsh^2
// ws layout (bytes):
//   xpad  bf16 [16][66][66][256] : 0          .. 35,684,352   (holds y, padded NHWC)
//   wsh   bf16 [9][256][256]     : 35,684,352 .. 36,864,000
//   s     f32  [16][256]         : 36,864,000 .. 36,880,384
//   G     f32  [256][256]        : 36,880,384 .. 37,142,528
//   demod f32  [16][256]         : 37,142,528 .. 37,158,912

#define WSH_OFF    35684352
#define S_OFF      36864000
#define G_OFF      36880384
#define DEMOD_OFF  37142528

typedef __attribute__((ext_vector_type(8))) short bf16x8;
typedef __attribute__((ext_vector_type(4))) float f32x4;
typedef __attribute__((ext_vector_type(4))) int i32x4;

#define GLOAD_LDS16(g, l)                                                        \
  __builtin_amdgcn_global_load_lds(                                              \
      (const __attribute__((address_space(1))) void*)(g),                        \
      (__attribute__((address_space(3))) void*)(l), 16, 0, 0)

__device__ __forceinline__ unsigned short f2bf(float f) {
  unsigned int u = __builtin_bit_cast(unsigned int, f);
  u += 0x7FFFu + ((u >> 16) & 1u);  // round-to-nearest-even
  return (unsigned short)(u >> 16);
}

// ---------------- kernel 1: style s[b][i]  +  shared weights & G ----------------
__global__ void prep1_k(const float* __restrict__ c_trg,
                        const float* __restrict__ style_w,
                        const float* __restrict__ style_b,
                        const float* __restrict__ weight,
                        float* __restrict__ s,
                        short* __restrict__ wsh,
                        float* __restrict__ G) {
  const int blk = blockIdx.x;
  const int tid = threadIdx.x;
  if (blk < 16) {
    const int b = blk;
    const float* ct = c_trg + b * 128;
    const float* sw = style_w + tid * 128;
    float acc = 0.f;
#pragma unroll 4
    for (int d = 0; d < 128; ++d) acc += ct[d] * sw[d];
    s[b * 256 + tid] = acc * 0.08838834764831845f + style_b[tid];  // 1/sqrt(128)
  } else {
    const int idx = (blk - 16) * 256 + tid;  // co*256+ci
    const float* wsrc = weight + idx * 9;    // 9 contiguous taps
    float g = 0.f;
#pragma unroll
    for (int t = 0; t < 9; ++t) {
      float v = wsrc[t] * 0.020833333333333332f;  // 1/sqrt(2304)
      g += v * v;
      wsh[t * 65536 + idx] = (short)f2bf(v);
    }
    G[idx] = g;
  }
}

// ---------------- kernel 2: y = s*x transpose + border zero + demod (fused grid) ----
__global__ void xpose_k(const float* __restrict__ x,
                        const float* __restrict__ s,
                        const float* __restrict__ G,
                        short* __restrict__ xpad,
                        float* __restrict__ demod) {
  __shared__ float tile[64][65];
  const int bid = blockIdx.x;
  const int tid = threadIdx.x;
  if (bid >= 4112) {
    // demod: block = b*256+co
    const int id = bid - 4112;
    const int b = id >> 8, co = id & 255;
    const float sv = s[b * 256 + tid];
    float ss = G[co * 256 + tid] * sv * sv;
#pragma unroll
    for (int o = 32; o; o >>= 1) ss += __shfl_down(ss, o);
    __shared__ float red[4];
    if ((tid & 63) == 0) red[tid >> 6] = ss;
    __syncthreads();
    if (tid == 0) demod[id] = rsqrtf(red[0] + red[1] + red[2] + red[3] + 1e-8f);
    return;
  }
  if (bid >= 4096) {
    const int b = bid - 4096;
    char* base = (char*)xpad + b * 66 * 66 * 512;
    const i32x4 z = {0, 0, 0, 0};
    for (int i = tid; i < 4224; i += 256) {
      const int r = i >= 2112;
      const int off = r * (65 * 66 * 512) + (i - r * 2112) * 16;
      *(i32x4*)(base + off) = z;
    }
    for (int i = tid; i < 4096; i += 256) {
      const int h = 1 + (i >> 6);
      const int side = (i >> 5) & 1;
      const int j = i & 31;
      *(i32x4*)(base + (h * 66 + side * 65) * 512 + j * 16) = z;
    }
    return;
  }
  const int ct = bid & 3;
  const int h = (bid >> 2) & 63;
  const int b = bid >> 8;
  const int w = tid & 63, cl = tid >> 6;
  const float* src = x + ((b * 256 + ct * 64) * 64 + h) * 64;
#pragma unroll
  for (int i = 0; i < 16; ++i) {
    int c = i * 4 + cl;
    tile[c][w] = src[c * 4096 + w];
  }
  const int cp = tid & 31;
  const float s0 = s[b * 256 + ct * 64 + cp * 2];
  const float s1 = s[b * 256 + ct * 64 + cp * 2 + 1];
  __syncthreads();
  short* dst = xpad + ((b * 66 + h + 1) * 66 + 1) * 256 + ct * 64;
#pragma unroll
  for (int i = 0; i < 8; ++i) {
    int idx = i * 256 + tid;
    int w2 = idx >> 5;  // 0..63
    unsigned int u = (unsigned int)f2bf(tile[cp * 2][w2] * s0) |
                     ((unsigned int)f2bf(tile[cp * 2 + 1][w2] * s1) << 16);
    *(unsigned int*)(dst + w2 * 256 + cp * 2) = u;
  }
}

// ---------------- kernel 3: implicit-GEMM conv, 256x256, BK=64, cross-tile reg hold --
// 512 thr = 8 waves (2M x 4N), wave tile 128x64. LDS = 2 dbuf x (A 32K + B 32K).
// 36 K-tiles (tap 0..8 x cc 0..3).
// r14 change vs r10: break the per-wave {read-wait -> MFMA} serialization by
// HOLDING the kc1 fragment set (a1[8],b1[4] = 48 VGPR) in registers ACROSS the
// tile boundary. Each tile then opens with an MFMA cluster whose operands are
// already in regs (zero lgkm dependency), issued right after the next read
// burst is queued -> the matrix pipe and LDS port overlap within every wave:
//   top:  vmcnt(0); s_barrier; SB     [buf(t) ready]
//   P1:   issue 12 ds_read R0(t)  ->  32 MFMA with R1(t-1) from held regs
//   mid:  s_barrier                   [deterministic: every wave's R1(t-1)
//                                      reads were lgkm-retired by its P1 MFMA]
//   P2:   issue 12 ds_read R1(t) -> stage(t+1) -> 32 MFMA R0(t) (counted lgkm)
// Race-freedom (deterministic): stage(t+1) writes buf((t+1)&1), which held tile
// t-1: R0(t-1) consumed in P2(t-1); R1(t-1) consumed in P1(t) BEFORE mid-barrier;
// stage(t+1) is issued after mid-barrier. vmcnt(0)+top barrier publishes staging.
// VGPR: acc 128 + held 48 + transient ~48 + addr ~30 -> fits 256 (2 waves/SIMD);
// r13 lesson: acc>128 spills catastrophically, this keeps acc=128.
// T1: XCD swizzle (grid 256). T2: XOR swizzle (0 conflicts, r7/r10-proven).
// No setprio / no intra-phase pins (r10/r11: null or negative).
__global__ __launch_bounds__(512, 2) void conv_k(const short* __restrict__ xpad,
                                                 const short* __restrict__ wsh,
                                                 const float* __restrict__ demod,
                                                 float* __restrict__ out) {
  extern __shared__ __align__(16) char lds[];  // 131072 B

  const int tid = threadIdx.x;
  const int lane = tid & 63;
  const int wid = tid >> 6;
  const int wm = wid >> 2;   // 0..1 : cout half
  const int wn = wid & 3;    // 0..3 : pixel quarter (output row r0+wn)

  const int orig = blockIdx.x;
  const int bid = (orig & 7) * 32 + (orig >> 3);  // T1
  const int b = bid >> 4;
  const int r0 = (bid & 15) * 4;  // 4 output rows per block

  // staging: per K-tile 8 x 16B loads/thread (A j0-3, B j0-3).
  const int t3 = tid >> 3;
  const int c16 = (tid & 7) * 16;
  const int swzc = c16 ^ ((t3 & 7) << 4);
  int aO[4], bO[4];
#pragma unroll
  for (int j = 0; j < 4; ++j) {
    aO[j] = (j * 64 + t3) * 512 + swzc;                   // + tap*131072 + cc*128
    bO[j] = ((b * 66 + r0 + j) * 66 + t3) * 512 + swzc;   // + (dh*66+dw)*512 + cc*128
  }
  const char* wB = (const char*)wsh;
  const char* xB = (const char*)xpad;

  auto stageA = [&](int ts) {
    const int tap = ts >> 2, cc = ts & 3;
    const int aAdd = tap * 131072 + cc * 128;
    char* d = lds + (ts & 1) * 65536;
#pragma unroll
    for (int j = 0; j < 4; ++j)
      GLOAD_LDS16(wB + aAdd + aO[j], d + j * 8192 + tid * 16);
  };
  auto stageB = [&](int ts) {
    const int tap = ts >> 2, cc = ts & 3;
    const int dh = (tap * 11) >> 5;  // tap/3
    const int bAdd = (dh * 66 + (tap - dh * 3)) * 512 + cc * 128;
    char* d = lds + (ts & 1) * 65536 + 32768;
#pragma unroll
    for (int j = 0; j < 4; ++j)
      GLOAD_LDS16(xB + bAdd + bO[j], d + j * 8192 + tid * 16);
  };

  // T2 read side: col_read = col ^ ((row&7)<<4); row&7 == lane&7 everywhere.
  const int xall = (lane & 7) << 4;
  const int xl = xall & 0x30;
  const int xh = xall & 0x40;
  const int colR = (((lane >> 4) << 4) ^ xl);
  const int ko0 = xh;
  const int ko1 = 64 ^ xh;
  const int aRdBase = (wm * 128 + (lane & 15)) * 128 + colR;
  const int bRdBase = 32768 + (wn * 64 + (lane & 15)) * 128 + colR;

  f32x4 acc[8][4] = {};
  bf16x8 a1[8], b1[4];  // held kc1 fragments (cross-tile)

  stageA(0);
  stageB(0);

  for (int t = 0; t < 36; ++t) {
    asm volatile("s_waitcnt vmcnt(0)" ::: "memory");
    __builtin_amdgcn_s_barrier();
    __builtin_amdgcn_sched_barrier(0);

    const char* Ab = lds + (t & 1) * 65536 + aRdBase;
    const char* Bb = lds + (t & 1) * 65536 + bRdBase;
    bf16x8 a0[8], b0[4];

    // ---- P1: issue R0(t) reads; MFMA R1(t-1) from held regs (no lgkm dep) ----
#pragma unroll
    for (int m = 0; m < 8; ++m) a0[m] = *(const bf16x8*)(Ab + m * 2048 + ko0);
#pragma unroll
    for (int n = 0; n < 4; ++n) b0[n] = *(const bf16x8*)(Bb + n * 2048 + ko0);
    if (t > 0) {
#pragma unroll
      for (int m = 0; m < 8; ++m)
#pragma unroll
        for (int n = 0; n < 4; ++n)
          acc[m][n] = __builtin_amdgcn_mfma_f32_16x16x32_bf16(a1[m], b1[n], acc[m][n], 0, 0, 0);
    }

    // ---- mid barrier: every wave's R1(t-1) reads retired by its P1 MFMA ----
    __builtin_amdgcn_s_barrier();
    __builtin_amdgcn_sched_barrier(0);

    // ---- P2: issue R1(t) reads into held regs; stage(t+1); MFMA R0(t) ----
#pragma unroll
    for (int m = 0; m < 8; ++m) a1[m] = *(const bf16x8*)(Ab + m * 2048 + ko1);
#pragma unroll
    for (int n = 0; n < 4; ++n) b1[n] = *(const bf16x8*)(Bb + n * 2048 + ko1);
    if (t + 1 < 36) {
      stageA(t + 1);
      stageB(t + 1);
    }
#pragma unroll
    for (int m = 0; m < 8; ++m)
#pragma unroll
      for (int n = 0; n < 4; ++n)
        acc[m][n] = __builtin_amdgcn_mfma_f32_16x16x32_bf16(a0[m], b0[n], acc[m][n], 0, 0, 0);

    asm volatile("" ::: "memory");
  }

  // drain: MFMA R1(35)
#pragma unroll
  for (int m = 0; m < 8; ++m)
#pragma unroll
    for (int n = 0; n < 4; ++n)
      acc[m][n] = __builtin_amdgcn_mfma_f32_16x16x32_bf16(a1[m], b1[n], acc[m][n], 0, 0, 0);

  // epilogue: scale by demod[b][cout], store fp32 NCHW.
  const int pc = lane & 15;
  const int rOff = (lane >> 4) * 4;
  const int h = r0 + wn;
#pragma unroll
  for (int m = 0; m < 8; ++m) {
#pragma unroll
    for (int r = 0; r < 4; ++r) {
      const int co = wm * 128 + m * 16 + rOff + r;
      const float dm = demod[(b << 8) + co];
      float* orow = out + (((b << 8) + co) << 12) + (h << 6);
#pragma unroll
      for (int n = 0; n < 4; ++n) {
        orow[n * 16 + pc] = acc[m][n][r] * dm;
      }
    }
  }
}

// ---------------- launcher ----------------
extern "C" void kernel_launch(void* const* d_in, const int* in_sizes, int n_in,
                              void* d_out, int out_size, void* d_ws, size_t ws_size,
                              hipStream_t stream) {
  const float* x       = (const float*)d_in[0];
  // d_in[1] = c_src (unused by reference)
  const float* c_trg   = (const float*)d_in[2];
  const float* style_w = (const float*)d_in[3];
  const float* style_b = (const float*)d_in[4];
  const float* weight  = (const float*)d_in[5];
  float* out = (float*)d_out;

  char* ws = (char*)d_ws;
  short* xpad  = (short*)(ws);
  short* wsh   = (short*)(ws + WSH_OFF);
  float* s     = (float*)(ws + S_OFF);
  float* G     = (float*)(ws + G_OFF);
  float* demod = (float*)(ws + DEMOD_OFF);

  hipFuncSetAttribute((const void*)conv_k,
                      hipFuncAttributeMaxDynamicSharedMemorySize, 131072);

  prep1_k<<<272, 256, 0, stream>>>(c_trg, style_w, style_b, weight, s, wsh, G);
  xpose_k<<<8208, 256, 0, stream>>>(x, s, G, xpad, demod);
  conv_k<<<256, 512, 131072, stream>>>(xpad, wsh, demod, out);
}

// Round 15
// 98.987 us; speedup vs baseline: 1.9245x; 1.0376x over previous
//
#include <hip/hip_runtime.h>

// ---------------- constants ----------------
// B=16, CIN=256, COUT=256, H=W=64, K=3, SDIM=128
// Separable reformulation:
//   out[b,co,p] = demod[b,co] * sum_{t,ci} wsh[t,co,ci] * y[b,ci,p+shift(t)]
//   wsh = conv_scale * w  (batch-independent!),  y = s[b,ci] * x[b,ci,p]
//   demod[b,co] = rsqrt( sum_ci G[co,ci] * s[b,ci]^2 + 1e-8 ),  G = sum_t wsh^2
// ws layout (bytes):
//   xpad  bf16 [16][66][66][256] : 0          .. 35,684,352   (holds y, padded NHWC)
//   wsh   bf16 [9][256][256]     : 35,684,352 .. 36,864,000
//   s     f32  [16][256]         : 36,864,000 .. 36,880,384
//   G     f32  [256][256]        : 36,880,384 .. 37,142,528
//   demod f32  [16][256]         : 37,142,528 .. 37,158,912

#define WSH_OFF    35684352
#define S_OFF      36864000
#define G_OFF      36880384
#define DEMOD_OFF  37142528

typedef __attribute__((ext_vector_type(8))) short bf16x8;
typedef __attribute__((ext_vector_type(4))) float f32x4;
typedef __attribute__((ext_vector_type(4))) int i32x4;

#define GLOAD_LDS16(g, l)                                                        \
  __builtin_amdgcn_global_load_lds(                                              \
      (const __attribute__((address_space(1))) void*)(g),                        \
      (__attribute__((address_space(3))) void*)(l), 16, 0, 0)

__device__ __forceinline__ unsigned short f2bf(float f) {
  unsigned int u = __builtin_bit_cast(unsigned int, f);
  u += 0x7FFFu + ((u >> 16) & 1u);  // round-to-nearest-even
  return (unsigned short)(u >> 16);
}

// ---------------- kernel 1: style s[b][i]  +  shared weights & G ----------------
__global__ void prep1_k(const float* __restrict__ c_trg,
                        const float* __restrict__ style_w,
                        const float* __restrict__ style_b,
                        const float* __restrict__ weight,
                        float* __restrict__ s,
                        short* __restrict__ wsh,
                        float* __restrict__ G) {
  const int blk = blockIdx.x;
  const int tid = threadIdx.x;
  if (blk < 16) {
    const int b = blk;
    const float* ct = c_trg + b * 128;
    const float* sw = style_w + tid * 128;
    float acc = 0.f;
#pragma unroll 4
    for (int d = 0; d < 128; ++d) acc += ct[d] * sw[d];
    s[b * 256 + tid] = acc * 0.08838834764831845f + style_b[tid];  // 1/sqrt(128)
  } else {
    const int idx = (blk - 16) * 256 + tid;  // co*256+ci
    const float* wsrc = weight + idx * 9;    // 9 contiguous taps
    float g = 0.f;
#pragma unroll
    for (int t = 0; t < 9; ++t) {
      float v = wsrc[t] * 0.020833333333333332f;  // 1/sqrt(2304)
      g += v * v;
      wsh[t * 65536 + idx] = (short)f2bf(v);
    }
    G[idx] = g;
  }
}

// ---------------- kernel 2: y = s*x transpose + border zero + demod (fused grid) ----
__global__ void xpose_k(const float* __restrict__ x,
                        const float* __restrict__ s,
                        const float* __restrict__ G,
                        short* __restrict__ xpad,
                        float* __restrict__ demod) {
  __shared__ float tile[64][65];
  const int bid = blockIdx.x;
  const int tid = threadIdx.x;
  if (bid >= 4112) {
    // demod: block = b*256+co
    const int id = bid - 4112;
    const int b = id >> 8, co = id & 255;
    const float sv = s[b * 256 + tid];
    float ss = G[co * 256 + tid] * sv * sv;
#pragma unroll
    for (int o = 32; o; o >>= 1) ss += __shfl_down(ss, o);
    __shared__ float red[4];
    if ((tid & 63) == 0) red[tid >> 6] = ss;
    __syncthreads();
    if (tid == 0) demod[id] = rsqrtf(red[0] + red[1] + red[2] + red[3] + 1e-8f);
    return;
  }
  if (bid >= 4096) {
    const int b = bid - 4096;
    char* base = (char*)xpad + b * 66 * 66 * 512;
    const i32x4 z = {0, 0, 0, 0};
    for (int i = tid; i < 4224; i += 256) {
      const int r = i >= 2112;
      const int off = r * (65 * 66 * 512) + (i - r * 2112) * 16;
      *(i32x4*)(base + off) = z;
    }
    for (int i = tid; i < 4096; i += 256) {
      const int h = 1 + (i >> 6);
      const int side = (i >> 5) & 1;
      const int j = i & 31;
      *(i32x4*)(base + (h * 66 + side * 65) * 512 + j * 16) = z;
    }
    return;
  }
  const int ct = bid & 3;
  const int h = (bid >> 2) & 63;
  const int b = bid >> 8;
  const int w = tid & 63, cl = tid >> 6;
  const float* src = x + ((b * 256 + ct * 64) * 64 + h) * 64;
#pragma unroll
  for (int i = 0; i < 16; ++i) {
    int c = i * 4 + cl;
    tile[c][w] = src[c * 4096 + w];
  }
  const int cp = tid & 31;
  const float s0 = s[b * 256 + ct * 64 + cp * 2];
  const float s1 = s[b * 256 + ct * 64 + cp * 2 + 1];
  __syncthreads();
  short* dst = xpad + ((b * 66 + h + 1) * 66 + 1) * 256 + ct * 64;
#pragma unroll
  for (int i = 0; i < 8; ++i) {
    int idx = i * 256 + tid;
    int w2 = idx >> 5;  // 0..63
    unsigned int u = (unsigned int)f2bf(tile[cp * 2][w2] * s0) |
                     ((unsigned int)f2bf(tile[cp * 2 + 1][w2] * s1) << 16);
    *(unsigned int*)(dst + w2 * 256 + cp * 2) = u;
  }
}

// ---------------- kernel 3: implicit-GEMM conv, 256x256, BK=64, drift (r10 best) ----
// 512 thr = 8 waves (2M x 4N), wave tile 128x64. LDS = 2 dbuf x (A 32K + B 32K).
// 36 K-tiles (tap 0..8 x cc 0..3). ONE sync point per tile (vmcnt(0)+barrier+SB);
// unpinned interior: compiler emits fine-grained counted lgkmcnt so each MFMA
// group starts as its operands land. Staging of tile t+1 (A at group 1, B at
// group 2) keeps loads in flight ~2/3 of the tile -> the tile-top vmcnt(0)
// drain is nearly free. This structure measured conv=68.4 µs, MfmaUtil 47%,
// 0 bank conflicts — the best of 8 structural variants (r4-r14); per-CU model:
// tile time ~= LDS-port(2816cy) + MFMA(2484cy) - overlap(~740cy).
// Race-freedom: stage(t+1) targets buf (t+1)&1 = tile t-1's buffer; its reads
// were data-dep-retired before each wave reached this tile's top barrier; the
// top vmcnt(0)+barrier publishes all waves' stage(t) writes.
// T1: XCD swizzle (grid 256) -> 2 samples per XCD L2.
// T2: XOR swizzle byte ^= ((row&7)<<4): linear LDS dest, inverse-swizzled
//     global source, swizzled ds_read; 16x16 frag rows span lane&15 -> 2-way
//     bank aliasing max = free (measured 0 conflicts).
__global__ __launch_bounds__(512, 2) void conv_k(const short* __restrict__ xpad,
                                                 const short* __restrict__ wsh,
                                                 const float* __restrict__ demod,
                                                 float* __restrict__ out) {
  extern __shared__ __align__(16) char lds[];  // 131072 B

  const int tid = threadIdx.x;
  const int lane = tid & 63;
  const int wid = tid >> 6;
  const int wm = wid >> 2;   // 0..1 : cout half
  const int wn = wid & 3;    // 0..3 : pixel quarter (output row r0+wn)

  const int orig = blockIdx.x;
  const int bid = (orig & 7) * 32 + (orig >> 3);  // T1
  const int b = bid >> 4;
  const int r0 = (bid & 15) * 4;  // 4 output rows per block

  // staging: per K-tile 8 x 16B loads/thread (A j0-3, B j0-3).
  // load j covers LDS rows j*64 + t3, byte col (tid&7)*16 (linear dest);
  // source col pre-swizzled: c16 ^ ((row&7)<<4), row&7 == t3&7.
  const int t3 = tid >> 3;
  const int c16 = (tid & 7) * 16;
  const int swzc = c16 ^ ((t3 & 7) << 4);
  int aO[4], bO[4];
#pragma unroll
  for (int j = 0; j < 4; ++j) {
    aO[j] = (j * 64 + t3) * 512 + swzc;                   // + tap*131072 + cc*128
    bO[j] = ((b * 66 + r0 + j) * 66 + t3) * 512 + swzc;   // + (dh*66+dw)*512 + cc*128
  }
  const char* wB = (const char*)wsh;
  const char* xB = (const char*)xpad;

  auto stageA = [&](int ts) {
    const int tap = ts >> 2, cc = ts & 3;
    const int aAdd = tap * 131072 + cc * 128;
    char* d = lds + (ts & 1) * 65536;
#pragma unroll
    for (int j = 0; j < 4; ++j)
      GLOAD_LDS16(wB + aAdd + aO[j], d + j * 8192 + tid * 16);
  };
  auto stageB = [&](int ts) {
    const int tap = ts >> 2, cc = ts & 3;
    const int dh = (tap * 11) >> 5;  // tap/3
    const int bAdd = (dh * 66 + (tap - dh * 3)) * 512 + cc * 128;
    char* d = lds + (ts & 1) * 65536 + 32768;
#pragma unroll
    for (int j = 0; j < 4; ++j)
      GLOAD_LDS16(xB + bAdd + bO[j], d + j * 8192 + tid * 16);
  };

  // T2 read side: col_read = col ^ ((row&7)<<4); row&7 == lane&7 everywhere.
  const int xall = (lane & 7) << 4;
  const int xl = xall & 0x30;
  const int xh = xall & 0x40;
  const int colR = (((lane >> 4) << 4) ^ xl);
  const int ko0 = xh;
  const int ko1 = 64 ^ xh;
  const int aRdBase = (wm * 128 + (lane & 15)) * 128 + colR;
  const int bRdBase = 32768 + (wn * 64 + (lane & 15)) * 128 + colR;

  f32x4 acc[8][4] = {};

  stageA(0);
  stageB(0);

  for (int t = 0; t < 36; ++t) {
    // single sync point per K-tile
    asm volatile("s_waitcnt vmcnt(0)" ::: "memory");
    __builtin_amdgcn_s_barrier();
    __builtin_amdgcn_sched_barrier(0);

    const char* Ab = lds + (t & 1) * 65536 + aRdBase;
    const char* Bb = lds + (t & 1) * 65536 + bRdBase;
    bf16x8 af[4][2], bq[2][2], bq2[2][2];

    // ---------- group 1 : reads A0-3, B0-1 ; stage A(t+1) ; MFMA (m0-3 x n0-1) -----
#pragma unroll
    for (int m = 0; m < 4; ++m) {
      af[m][0] = *(const bf16x8*)(Ab + m * 2048 + ko0);
      af[m][1] = *(const bf16x8*)(Ab + m * 2048 + ko1);
    }
#pragma unroll
    for (int n = 0; n < 2; ++n) {
      bq[n][0] = *(const bf16x8*)(Bb + n * 2048 + ko0);
      bq[n][1] = *(const bf16x8*)(Bb + n * 2048 + ko1);
    }
    if (t + 1 < 36) stageA(t + 1);
#pragma unroll
    for (int m = 0; m < 4; ++m)
#pragma unroll
      for (int n = 0; n < 2; ++n) {
        acc[m][n] = __builtin_amdgcn_mfma_f32_16x16x32_bf16(af[m][0], bq[n][0], acc[m][n], 0, 0, 0);
        acc[m][n] = __builtin_amdgcn_mfma_f32_16x16x32_bf16(af[m][1], bq[n][1], acc[m][n], 0, 0, 0);
      }

    // ---------- group 2 : reads B2-3 ; stage B(t+1) ; MFMA (m0-3 x n2-3) -----------
#pragma unroll
    for (int n = 0; n < 2; ++n) {
      bq2[n][0] = *(const bf16x8*)(Bb + (n + 2) * 2048 + ko0);
      bq2[n][1] = *(const bf16x8*)(Bb + (n + 2) * 2048 + ko1);
    }
    if (t + 1 < 36) stageB(t + 1);
#pragma unroll
    for (int m = 0; m < 4; ++m)
#pragma unroll
      for (int n = 0; n < 2; ++n) {
        acc[m][n + 2] = __builtin_amdgcn_mfma_f32_16x16x32_bf16(af[m][0], bq2[n][0], acc[m][n + 2], 0, 0, 0);
        acc[m][n + 2] = __builtin_amdgcn_mfma_f32_16x16x32_bf16(af[m][1], bq2[n][1], acc[m][n + 2], 0, 0, 0);
      }

    // ---------- group 3 : reads A4-7 ; MFMA (m4-7 x n0-3) --------------------------
#pragma unroll
    for (int m = 0; m < 4; ++m) {
      af[m][0] = *(const bf16x8*)(Ab + (m + 4) * 2048 + ko0);
      af[m][1] = *(const bf16x8*)(Ab + (m + 4) * 2048 + ko1);
    }
#pragma unroll
    for (int m = 0; m < 4; ++m)
#pragma unroll
      for (int n = 0; n < 2; ++n) {
        acc[m + 4][n] = __builtin_amdgcn_mfma_f32_16x16x32_bf16(af[m][0], bq[n][0], acc[m + 4][n], 0, 0, 0);
        acc[m + 4][n] = __builtin_amdgcn_mfma_f32_16x16x32_bf16(af[m][1], bq[n][1], acc[m + 4][n], 0, 0, 0);
        acc[m + 4][n + 2] = __builtin_amdgcn_mfma_f32_16x16x32_bf16(af[m][0], bq2[n][0], acc[m + 4][n + 2], 0, 0, 0);
        acc[m + 4][n + 2] = __builtin_amdgcn_mfma_f32_16x16x32_bf16(af[m][1], bq2[n][1], acc[m + 4][n + 2], 0, 0, 0);
      }
    asm volatile("" ::: "memory");
  }

  // epilogue: scale by demod[b][cout], store fp32 NCHW.
  const int pc = lane & 15;
  const int rOff = (lane >> 4) * 4;
  const int h = r0 + wn;
#pragma unroll
  for (int m = 0; m < 8; ++m) {
#pragma unroll
    for (int r = 0; r < 4; ++r) {
      const int co = wm * 128 + m * 16 + rOff + r;
      const float dm = demod[(b << 8) + co];
      float* orow = out + (((b << 8) + co) << 12) + (h << 6);
#pragma unroll
      for (int n = 0; n < 4; ++n) {
        orow[n * 16 + pc] = acc[m][n][r] * dm;
      }
    }
  }
}

// ---------------- launcher ----------------
extern "C" void kernel_launch(void* const* d_in, const int* in_sizes, int n_in,
                              void* d_out, int out_size, void* d_ws, size_t ws_size,
                              hipStream_t stream) {
  const float* x       = (const float*)d_in[0];
  // d_in[1] = c_src (unused by reference)
  const float* c_trg   = (const float*)d_in[2];
  const float* style_w = (const float*)d_in[3];
  const float* style_b = (const float*)d_in[4];
  const float* weight  = (const float*)d_in[5];
  float* out = (float*)d_out;

  char* ws = (char*)d_ws;
  short* xpad  = (short*)(ws);
  short* wsh   = (short*)(ws + WSH_OFF);
  float* s     = (float*)(ws + S_OFF);
  float* G     = (float*)(ws + G_OFF);
  float* demod = (float*)(ws + DEMOD_OFF);

  hipFuncSetAttribute((const void*)conv_k,
                      hipFuncAttributeMaxDynamicSharedMemorySize, 131072);

  prep1_k<<<272, 256, 0, stream>>>(c_trg, style_w, style_b, weight, s, wsh, G);
  xpose_k<<<8208, 256, 0, stream>>>(x, s, G, xpad, demod);
  conv_k<<<256, 512, 131072, stream>>>(xpad, wsh, demod, out);
}